// Round 10
// baseline (6107.743 us; speedup 1.0000x reference)
//
#include <hip/hip_runtime.h>

// LSTM forward, B=32 T=1024 D=512 U=512, fp32.
// Persistent fused kernel, 256 WGs x 512 thr (all co-resident, grid == #CUs).
//
// R10: 2-deep GROUP INTERLEAVE with replica redundancy.
// WG i (u = i>>3: units [16u,16u+16), q = i&7): runs TWO independent
// recurrences, phase A = group q (batches 4q..4q+3), phase B = group q^1,
// with the SAME R/K weight slices (weights are batch-independent!).
// Group g is computed redundantly by set {i&7==g} (phase A) and {i&7==g^1}
// (phase B): bit-identical fp32 duplicates -> duplicate stores benign, and
// consumers' sentinel polls are satisfied by whichever replica lands first
// (min-of-2 cuts the straggler tail). The A-replica of h_g(t-1) lands ~one
// phase before the next A-phase polls it -> LLC store latency + skew hide
// behind the opposite phase's compute.
// Per phase: R9's proven structure exactly (slice-local sentinel data-poll,
// wave-private LH staging, f32x2 packed dot, LR partials (phase-indexed,
// race-free via B2 ordering), distributed per-wave gates, per-phase xz ring).

#define TT 1024
#define DD 512
#define UU 512
#define NCOL 2048
#define SENT 0xFFFFFFFFu
#define RDEPTH 2

typedef float f32x2 __attribute__((ext_vector_type(2)));
typedef float f32x4 __attribute__((ext_vector_type(4)));

__device__ __forceinline__ float hsig(float v) {
  return fminf(fmaxf(0.2f * v + 0.5f, 0.0f), 1.0f);
}
__device__ __forceinline__ float tanh_fast(float x) {
  float e = __expf(2.0f * x);
  return 1.0f - 2.0f / (e + 1.0f);
}

// Epoch barrier for the 4 waves of one half (waves 0-3 or 4-7).
template <bool SLEEP>
__device__ __forceinline__ void wavebar(int* ctr, int& ep) {
  asm volatile("s_waitcnt lgkmcnt(0)" ::: "memory");
  if ((threadIdx.x & 63) == 0)
    __hip_atomic_fetch_add(ctr, 1, __ATOMIC_RELAXED, __HIP_MEMORY_SCOPE_WORKGROUP);
  ep += 4;
  while (__hip_atomic_load(ctr, __ATOMIC_RELAXED, __HIP_MEMORY_SCOPE_WORKGROUP) < ep) {
    if (SLEEP) __builtin_amdgcn_s_sleep(1);
  }
  asm volatile("" ::: "memory");
}

__global__ __launch_bounds__(512, 2) void lstm_persistent(
    const float* __restrict__ x,
    const float* __restrict__ Wk,
    const float* __restrict__ Wr,
    const float* __restrict__ bias,
    float* __restrict__ out) {
  const int tid = (int)threadIdx.x;
  const int i   = (int)blockIdx.x;
  const int u   = i >> 3;          // unit block: units [16u, 16u+16)
  const int q   = i & 7;
  const int grp[2] = {q, q ^ 1};   // phase A group, phase B group
  const bool crit = (tid < 256);
  const int l   = tid & 63;

  __shared__ float LX[8][4][65];          // xz partials (serially reused A/B)
  __shared__ float LR[2][8][4][66];       // recurrent partials, [phase]
  __shared__ float RING[2][RDEPTH][4][66];// reduced xz ring, [phase]
  __shared__ float LH[4][8][68];          // h(t-1) staged (wave-private octants)
  __shared__ float LB[64];                // bias slice
  __shared__ int cXZdone[2], cCRITdone[2], cXZbar, cCRITbar;

  if (tid < 2) { cXZdone[tid] = 0; cCRITdone[tid] = 0; }
  if (tid == 0) { cXZbar = 0; cCRITbar = 0; }
  if (tid < 64) LB[tid] = bias[(tid >> 4) * UU + u * 16 + (tid & 15)];

  // ---- weight slices in VGPRs (f32x2 col-pairs); SHARED by both phases ----
  f32x2 W2[64];
  {
    const int wv  = tid >> 6;
    const int idx = tid & 255;
    const int cp  = crit ? (l & 31) : (idx & 31);
    const int ko  = crit ? (2 * (wv & 3) + (l >> 5)) : (idx >> 5);
    const int gcb = (cp >> 3) * UU + u * 16 + ((2 * cp) & 15);
    const float* M = crit ? Wr : Wk;
#pragma unroll
    for (int j = 0; j < 64; ++j)
      W2[j] = *(const f32x2*)(M + (size_t)(64 * ko + j) * NCOL + gcb);
  }
  __syncthreads();  // one-time init barrier only

  if (crit) {
    // ---------------- critical path: waves 0-3, two phases per loop -------
    const int wv  = tid >> 6;        // wave id; poll-slice + batch-in-group wv
    const int kq0 = 2 * wv;
    const int kql = kq0 + (l >> 5);
    const int cp  = l & 31;
    float c_state[2] = {0.0f, 0.0f};
    int epC = 0;
    const unsigned* oub[2][4];
#pragma unroll
    for (int ph = 0; ph < 2; ++ph)
#pragma unroll
      for (int k = 0; k < 4; ++k)
        oub[ph][k] = (const unsigned*)out + (size_t)(grp[ph] * 4 + k) * TT * UU;

    for (int t = 0; t < TT; ++t) {
#pragma unroll
      for (int ph = 0; ph < 2; ++ph) {
        if (t > 0) {
          // ---- slice-local data-poll: 8 words, 1 RTT ----
          const size_t roff = (size_t)(t - 1) * UU + 128 * wv + l;
          unsigned v0, v1, v2, v3, v4, v5, v6, v7;
          for (;;) {
            v0 = __hip_atomic_load(oub[ph][0] + roff,      __ATOMIC_RELAXED, __HIP_MEMORY_SCOPE_AGENT);
            v1 = __hip_atomic_load(oub[ph][0] + roff + 64, __ATOMIC_RELAXED, __HIP_MEMORY_SCOPE_AGENT);
            v2 = __hip_atomic_load(oub[ph][1] + roff,      __ATOMIC_RELAXED, __HIP_MEMORY_SCOPE_AGENT);
            v3 = __hip_atomic_load(oub[ph][1] + roff + 64, __ATOMIC_RELAXED, __HIP_MEMORY_SCOPE_AGENT);
            v4 = __hip_atomic_load(oub[ph][2] + roff,      __ATOMIC_RELAXED, __HIP_MEMORY_SCOPE_AGENT);
            v5 = __hip_atomic_load(oub[ph][2] + roff + 64, __ATOMIC_RELAXED, __HIP_MEMORY_SCOPE_AGENT);
            v6 = __hip_atomic_load(oub[ph][3] + roff,      __ATOMIC_RELAXED, __HIP_MEMORY_SCOPE_AGENT);
            v7 = __hip_atomic_load(oub[ph][3] + roff + 64, __ATOMIC_RELAXED, __HIP_MEMORY_SCOPE_AGENT);
            int ok = (v0 != SENT) & (v1 != SENT) & (v2 != SENT) & (v3 != SENT) &
                     (v4 != SENT) & (v5 != SENT) & (v6 != SENT) & (v7 != SENT);
            if (__all(ok)) break;
            __builtin_amdgcn_s_sleep(1);
          }
          // ---- stage into this wave's private LH octants ----
          LH[0][kq0    ][l] = __uint_as_float(v0);
          LH[0][kq0 + 1][l] = __uint_as_float(v1);
          LH[1][kq0    ][l] = __uint_as_float(v2);
          LH[1][kq0 + 1][l] = __uint_as_float(v3);
          LH[2][kq0    ][l] = __uint_as_float(v4);
          LH[2][kq0 + 1][l] = __uint_as_float(v5);
          LH[3][kq0    ][l] = __uint_as_float(v6);
          LH[3][kq0 + 1][l] = __uint_as_float(v7);
          asm volatile("s_waitcnt lgkmcnt(0)" ::: "memory");
          __builtin_amdgcn_sched_barrier(0);
          // ---- dot: 2 cols x 64 k x 4 batches, f32x2 acc (v_pk_fma) ----
          __builtin_amdgcn_s_setprio(1);
          f32x2 a0 = {0.f, 0.f}, a1 = {0.f, 0.f}, a2 = {0.f, 0.f}, a3 = {0.f, 0.f};
#pragma unroll
          for (int j4 = 0; j4 < 16; ++j4) {
            f32x4 h0 = *(const f32x4*)&LH[0][kql][4 * j4];
            f32x4 h1 = *(const f32x4*)&LH[1][kql][4 * j4];
            f32x4 h2 = *(const f32x4*)&LH[2][kql][4 * j4];
            f32x4 h3 = *(const f32x4*)&LH[3][kql][4 * j4];
#pragma unroll
            for (int jj = 0; jj < 4; ++jj) {
              f32x2 wj = W2[4 * j4 + jj];
              a0 += (f32x2){h0[jj], h0[jj]} * wj;
              a1 += (f32x2){h1[jj], h1[jj]} * wj;
              a2 += (f32x2){h2[jj], h2[jj]} * wj;
              a3 += (f32x2){h3[jj], h3[jj]} * wj;
            }
          }
          __builtin_amdgcn_s_setprio(0);
          *(f32x2*)&LR[ph][kql][0][2 * cp] = a0;
          *(f32x2*)&LR[ph][kql][1][2 * cp] = a1;
          *(f32x2*)&LR[ph][kql][2][2 * cp] = a2;
          *(f32x2*)&LR[ph][kql][3][2 * cp] = a3;
        }
        // ---- pre-gate: xz + bias for batch wv (lanes 0-15), before B2 ----
        float s0 = 0.f, s1 = 0.f, s2 = 0.f, s3 = 0.f;
        if (l < 16) {
          while (__hip_atomic_load(&cXZdone[ph], __ATOMIC_RELAXED,
                                   __HIP_MEMORY_SCOPE_WORKGROUP) < t + 1) {
          }
          asm volatile("" ::: "memory");
          const int ss = t & (RDEPTH - 1);
          s0 = RING[ph][ss][wv][l +  0] + LB[l +  0];
          s1 = RING[ph][ss][wv][l + 16] + LB[l + 16];
          s2 = RING[ph][ss][wv][l + 32] + LB[l + 32];
          s3 = RING[ph][ss][wv][l + 48] + LB[l + 48];
        }
        wavebar<false>(&cCRITbar, epC);  // B2: all LR partials complete
        if (l == 0)
          __hip_atomic_fetch_add(&cCRITdone[ph], 1, __ATOMIC_RELAXED,
                                 __HIP_MEMORY_SCOPE_WORKGROUP);
        // ---- gates for batch (grp[ph]*4+wv), units [16u,16u+16) ----
        if (l < 16) {
          if (t > 0) {
#pragma unroll
            for (int kq = 0; kq < 8; ++kq) {
              s0 += LR[ph][kq][wv][l +  0];
              s1 += LR[ph][kq][wv][l + 16];
              s2 += LR[ph][kq][wv][l + 32];
              s3 += LR[ph][kq][wv][l + 48];
            }
          }
          float gi = hsig(s0);
          float gf = hsig(s1);
          float gc = tanh_fast(s2);
          float go = hsig(s3);
          c_state[ph] = gf * c_state[ph] + gi * gc;
          float h = go * tanh_fast(c_state[ph]);
          __hip_atomic_store(
              out + ((size_t)(grp[ph] * 4 + wv) * TT + t) * UU + u * 16 + l, h,
              __ATOMIC_RELAXED, __HIP_MEMORY_SCOPE_AGENT);
        }
      }
    }
  } else {
    // ---------------- xz pipeline: waves 4-7, two tiles per loop ----------
    const int idx = tid & 255;
    const int o   = idx >> 5;
    const int cp  = idx & 31;
    int epX = 0;
    const float* xb[2][4];
#pragma unroll
    for (int ph = 0; ph < 2; ++ph)
#pragma unroll
      for (int k = 0; k < 4; ++k)
        xb[ph][k] = x + (size_t)(grp[ph] * 4 + k) * TT * DD + o * 64;

    for (int t = 0; t < TT; ++t) {
#pragma unroll
      for (int ph = 0; ph < 2; ++ph) {
        const size_t off = (size_t)t * DD;
        f32x2 a0 = {0.f, 0.f}, a1 = {0.f, 0.f}, a2 = {0.f, 0.f}, a3 = {0.f, 0.f};
#pragma unroll
        for (int j4 = 0; j4 < 16; ++j4) {
          f32x4 v0 = *(const f32x4*)(xb[ph][0] + off + 4 * j4);
          f32x4 v1 = *(const f32x4*)(xb[ph][1] + off + 4 * j4);
          f32x4 v2 = *(const f32x4*)(xb[ph][2] + off + 4 * j4);
          f32x4 v3 = *(const f32x4*)(xb[ph][3] + off + 4 * j4);
#pragma unroll
          for (int jj = 0; jj < 4; ++jj) {
            f32x2 wj = W2[4 * j4 + jj];
            a0 += (f32x2){v0[jj], v0[jj]} * wj;
            a1 += (f32x2){v1[jj], v1[jj]} * wj;
            a2 += (f32x2){v2[jj], v2[jj]} * wj;
            a3 += (f32x2){v3[jj], v3[jj]} * wj;
          }
        }
        *(f32x2*)&LX[o][0][2 * cp] = a0;
        *(f32x2*)&LX[o][1][2 * cp] = a1;
        *(f32x2*)&LX[o][2][2 * cp] = a2;
        *(f32x2*)&LX[o][3][2 * cp] = a3;
        wavebar<true>(&cXZbar, epX);  // partials visible
        // ring slot (t & 1) free? (crit consumed tile t-RDEPTH of this phase)
        if (t >= RDEPTH) {
          while (__hip_atomic_load(&cCRITdone[ph], __ATOMIC_RELAXED,
                                   __HIP_MEMORY_SCOPE_WORKGROUP) <
                 4 * (t - RDEPTH + 1)) {
            __builtin_amdgcn_s_sleep(1);
          }
          asm volatile("" ::: "memory");
        }
        {
          const int b2 = idx >> 6, c3 = idx & 63;
          float ssum = 0.f;
#pragma unroll
          for (int oo = 0; oo < 8; ++oo) ssum += LX[oo][b2][c3];
          RING[ph][t & (RDEPTH - 1)][b2][c3] = ssum;
        }
        wavebar<true>(&cXZbar, epX);  // reduce complete (guards LX overwrite)
        if (idx == 0) {
          asm volatile("s_waitcnt lgkmcnt(0)" ::: "memory");
          __hip_atomic_fetch_add(&cXZdone[ph], 1, __ATOMIC_RELAXED,
                                 __HIP_MEMORY_SCOPE_WORKGROUP);
        }
      }
    }
  }
}

extern "C" void kernel_launch(void* const* d_in, const int* in_sizes, int n_in,
                              void* d_out, int out_size, void* d_ws, size_t ws_size,
                              hipStream_t stream) {
  const float* x    = (const float*)d_in[0];
  const float* Wk   = (const float*)d_in[1];
  const float* Wr   = (const float*)d_in[2];
  const float* bias = (const float*)d_in[3];
  float* out = (float*)d_out;

  // Sentinel-fill the h history (graph-capturable async memset).
  hipMemsetAsync(out, 0xFF, (size_t)out_size * sizeof(float), stream);
  lstm_persistent<<<256, 512, 0, stream>>>(x, Wk, Wr, bias, out);
}

// Round 12
// 4834.293 us; speedup vs baseline: 1.2634x; 1.2634x over previous
//
#include <hip/hip_runtime.h>

// LSTM forward, B=32 T=1024 D=512 U=512, fp32.
// Persistent fused kernel, 256 WGs x 512 thr (all co-resident, grid == #CUs).
// Group g = blockIdx&7 (batches 4g..4g+3); WG w = blockIdx>>3 owns units
// [16w,16w+16). Weights in VGPRs as f32x2 col-pairs. Base = R9 (best).
//
// R12 = R9 + three additive shaves (no new sync mechanisms; LLC-only):
//  1. software-pipelined DOUBLE poll (streams A/B interleaved): a sentinel
//     check completes every ~RTT/2 instead of every RTT (LLVM partial
//     s_waitcnt vmcnt(8) gives the stagger). No sleep in crit poll.
//  2. parallelized tail: 64 lanes, lane (gate=l>>4, u=l&15) sums its own
//     gate's LR column (8 LDS reads), shfl_xor(16/32) gate gather (R8-proven
//     mux), 4x redundant deterministic c_state, gsel==0 lanes store h.
//     Pre-gate xz+bias is ONE LDS read: RING[ss][wv][l] + LB[l].
//  3. cCRITdone signaled immediately after the RING read (not after B2).

#define TT 1024
#define DD 512
#define UU 512
#define NCOL 2048
#define SENT 0xFFFFFFFFu
#define RDEPTH 4

typedef float f32x2 __attribute__((ext_vector_type(2)));
typedef float f32x4 __attribute__((ext_vector_type(4)));

__device__ __forceinline__ float hsig(float v) {
  return fminf(fmaxf(0.2f * v + 0.5f, 0.0f), 1.0f);
}
__device__ __forceinline__ float tanh_fast(float x) {
  float e = __expf(2.0f * x);
  return 1.0f - 2.0f / (e + 1.0f);
}

template <bool SLEEP>
__device__ __forceinline__ void wavebar(int* ctr, int& ep) {
  asm volatile("s_waitcnt lgkmcnt(0)" ::: "memory");
  if ((threadIdx.x & 63) == 0)
    __hip_atomic_fetch_add(ctr, 1, __ATOMIC_RELAXED, __HIP_MEMORY_SCOPE_WORKGROUP);
  ep += 4;
  while (__hip_atomic_load(ctr, __ATOMIC_RELAXED, __HIP_MEMORY_SCOPE_WORKGROUP) < ep) {
    if (SLEEP) __builtin_amdgcn_s_sleep(1);
  }
  asm volatile("" ::: "memory");
}

#define AL(p) __hip_atomic_load((p), __ATOMIC_RELAXED, __HIP_MEMORY_SCOPE_AGENT)
#define L8(q0,q1,q2,q3,q4,q5,q6,q7)                                  \
  q0 = AL(ou0 + roff); q1 = AL(ou0 + roff + 64);                     \
  q2 = AL(ou1 + roff); q3 = AL(ou1 + roff + 64);                     \
  q4 = AL(ou2 + roff); q5 = AL(ou2 + roff + 64);                     \
  q6 = AL(ou3 + roff); q7 = AL(ou3 + roff + 64);
#define OK8(q0,q1,q2,q3,q4,q5,q6,q7)                                 \
  ((q0 != SENT) & (q1 != SENT) & (q2 != SENT) & (q3 != SENT) &       \
   (q4 != SENT) & (q5 != SENT) & (q6 != SENT) & (q7 != SENT))

__global__ __launch_bounds__(512, 2) void lstm_persistent(
    const float* __restrict__ x,
    const float* __restrict__ Wk,
    const float* __restrict__ Wr,
    const float* __restrict__ bias,
    float* __restrict__ out) {
  const int tid = (int)threadIdx.x;
  const int g   = (int)blockIdx.x & 7;
  const int w   = (int)blockIdx.x >> 3;
  const bool crit = (tid < 256);
  const int l   = tid & 63;

  __shared__ float LX[8][4][65];
  __shared__ float LR[2][8][4][66];
  __shared__ float RING[RDEPTH][4][66];
  __shared__ float LH[4][8][68];
  __shared__ float LB[64];
  __shared__ int cXZdone, cCRITdone, cXZbar, cCRITbar;

  if (tid == 0) { cXZdone = 0; cCRITdone = 0; cXZbar = 0; cCRITbar = 0; }
  if (tid < 64) LB[tid] = bias[(tid >> 4) * UU + w * 16 + (tid & 15)];

  f32x2 W2[64];
  {
    const int wv  = tid >> 6;
    const int idx = tid & 255;
    const int cp  = crit ? (l & 31) : (idx & 31);
    const int ko  = crit ? (2 * (wv & 3) + (l >> 5)) : (idx >> 5);
    const int gcb = (cp >> 3) * UU + w * 16 + ((2 * cp) & 15);
    const float* M = crit ? Wr : Wk;
#pragma unroll
    for (int j = 0; j < 64; ++j)
      W2[j] = *(const f32x2*)(M + (size_t)(64 * ko + j) * NCOL + gcb);
  }
  __syncthreads();  // one-time init barrier only

  if (crit) {
    // ---------------- critical path: waves 0-3 ----------------
    const int wv   = tid >> 6;       // wave id; poll-slice + batch wv
    const int kq0  = 2 * wv;
    const int kql  = kq0 + (l >> 5);
    const int cp   = l & 31;
    const int gsel = l >> 4;         // gate of this lane (0..3)
    const unsigned* ou0 = (const unsigned*)out + (size_t)(g * 4 + 0) * TT * UU;
    const unsigned* ou1 = (const unsigned*)out + (size_t)(g * 4 + 1) * TT * UU;
    const unsigned* ou2 = (const unsigned*)out + (size_t)(g * 4 + 2) * TT * UU;
    const unsigned* ou3 = (const unsigned*)out + (size_t)(g * 4 + 3) * TT * UU;
    float c_state = 0.0f;            // per-lane copy for (batch wv, unit l&15)
    int epC = 0;

    for (int t = 0; t < TT; ++t) {
      if (t > 0) {
        const size_t roff = (size_t)(t - 1) * UU + 128 * wv + l;
        unsigned a0,a1,a2,a3,a4,a5,a6,a7;
        unsigned b0,b1,b2,b3,b4,b5,b6,b7;
        // ---- pipelined double poll: check completes every ~RTT/2 ----
        L8(a0,a1,a2,a3,a4,a5,a6,a7);
        for (;;) {
          L8(b0,b1,b2,b3,b4,b5,b6,b7);
          if (__all(OK8(a0,a1,a2,a3,a4,a5,a6,a7))) break;
          L8(a0,a1,a2,a3,a4,a5,a6,a7);
          if (__all(OK8(b0,b1,b2,b3,b4,b5,b6,b7))) {
            a0=b0; a1=b1; a2=b2; a3=b3; a4=b4; a5=b5; a6=b6; a7=b7;
            break;
          }
        }
        // ---- stage into this wave's private LH octants ----
        LH[0][kq0    ][l] = __uint_as_float(a0);
        LH[0][kq0 + 1][l] = __uint_as_float(a1);
        LH[1][kq0    ][l] = __uint_as_float(a2);
        LH[1][kq0 + 1][l] = __uint_as_float(a3);
        LH[2][kq0    ][l] = __uint_as_float(a4);
        LH[2][kq0 + 1][l] = __uint_as_float(a5);
        LH[3][kq0    ][l] = __uint_as_float(a6);
        LH[3][kq0 + 1][l] = __uint_as_float(a7);
        asm volatile("s_waitcnt lgkmcnt(0)" ::: "memory");
        __builtin_amdgcn_sched_barrier(0);
        // ---- dot: 2 cols x 64 k x 4 batches, f32x2 acc (v_pk_fma) ----
        __builtin_amdgcn_s_setprio(1);
        f32x2 d0 = {0.f,0.f}, d1 = {0.f,0.f}, d2 = {0.f,0.f}, d3 = {0.f,0.f};
#pragma unroll
        for (int j4 = 0; j4 < 16; ++j4) {
          f32x4 h0 = *(const f32x4*)&LH[0][kql][4 * j4];
          f32x4 h1 = *(const f32x4*)&LH[1][kql][4 * j4];
          f32x4 h2 = *(const f32x4*)&LH[2][kql][4 * j4];
          f32x4 h3 = *(const f32x4*)&LH[3][kql][4 * j4];
#pragma unroll
          for (int jj = 0; jj < 4; ++jj) {
            f32x2 wj = W2[4 * j4 + jj];
            d0 += (f32x2){h0[jj], h0[jj]} * wj;
            d1 += (f32x2){h1[jj], h1[jj]} * wj;
            d2 += (f32x2){h2[jj], h2[jj]} * wj;
            d3 += (f32x2){h3[jj], h3[jj]} * wj;
          }
        }
        __builtin_amdgcn_s_setprio(0);
        const int p = t & 1;
        *(f32x2*)&LR[p][kql][0][2 * cp] = d0;
        *(f32x2*)&LR[p][kql][1][2 * cp] = d1;
        *(f32x2*)&LR[p][kql][2][2 * cp] = d2;
        *(f32x2*)&LR[p][kql][3][2 * cp] = d3;
      }
      // ---- pre-gate: xz + bias, ONE LDS read per lane (col l) ----
      while (__hip_atomic_load(&cXZdone, __ATOMIC_RELAXED,
                               __HIP_MEMORY_SCOPE_WORKGROUP) < t + 1) {
      }
      asm volatile("" ::: "memory");
      float s = RING[t & (RDEPTH - 1)][wv][l] + LB[l];
      if (l == 0)
        __hip_atomic_fetch_add(&cCRITdone, 1, __ATOMIC_RELAXED,
                               __HIP_MEMORY_SCOPE_WORKGROUP);
      wavebar<false>(&cCRITbar, epC);  // B2: all LR partials complete
      if (t > 0) {
        const int p = t & 1;
#pragma unroll
        for (int kq = 0; kq < 8; ++kq) s += LR[p][kq][wv][l];
      }
      // ---- gate gather: value of gate q for unit u lives in lane 16q+u ----
      float za  = __shfl_xor(s, 16);   // gate gsel^1
      float zb  = __shfl_xor(s, 32);   // gate gsel^2
      float zc2 = __shfl_xor(za, 32);  // gate gsel^3
      float zi  = gsel == 0 ? s   : gsel == 1 ? za  : gsel == 2 ? zb  : zc2;
      float zf  = gsel == 0 ? za  : gsel == 1 ? s   : gsel == 2 ? zc2 : zb;
      float zc_ = gsel == 0 ? zb  : gsel == 1 ? zc2 : gsel == 2 ? s   : za;
      float zo  = gsel == 0 ? zc2 : gsel == 1 ? zb  : gsel == 2 ? za  : s;
      float gi = hsig(zi);
      float gf = hsig(zf);
      float gc = tanh_fast(zc_);
      float go = hsig(zo);
      c_state = gf * c_state + gi * gc;  // 4 redundant identical copies/unit
      float h = go * tanh_fast(c_state);
      if (gsel == 0) {  // 16 lanes store: (batch wv, unit w*16 + (l&15))
        __hip_atomic_store(
            out + ((size_t)(g * 4 + wv) * TT + t) * UU + w * 16 + l, h,
            __ATOMIC_RELAXED, __HIP_MEMORY_SCOPE_AGENT);
      }
    }
  } else {
    // ---------------- xz pipeline: waves 4-7 (free-running) ----------------
    const int idx = tid & 255;
    const int o   = idx >> 5;
    const int cp  = idx & 31;
    const float* xb0 = x + (size_t)(g * 4 + 0) * TT * DD + o * 64;
    const float* xb1 = x + (size_t)(g * 4 + 1) * TT * DD + o * 64;
    const float* xb2 = x + (size_t)(g * 4 + 2) * TT * DD + o * 64;
    const float* xb3 = x + (size_t)(g * 4 + 3) * TT * DD + o * 64;
    int epX = 0;

    for (int t = 0; t < TT; ++t) {
      const size_t off = (size_t)t * DD;
      f32x2 a0 = {0.f,0.f}, a1 = {0.f,0.f}, a2 = {0.f,0.f}, a3 = {0.f,0.f};
#pragma unroll
      for (int j4 = 0; j4 < 16; ++j4) {
        f32x4 v0 = *(const f32x4*)(xb0 + off + 4 * j4);
        f32x4 v1 = *(const f32x4*)(xb1 + off + 4 * j4);
        f32x4 v2 = *(const f32x4*)(xb2 + off + 4 * j4);
        f32x4 v3 = *(const f32x4*)(xb3 + off + 4 * j4);
#pragma unroll
        for (int jj = 0; jj < 4; ++jj) {
          f32x2 wj = W2[4 * j4 + jj];
          a0 += (f32x2){v0[jj], v0[jj]} * wj;
          a1 += (f32x2){v1[jj], v1[jj]} * wj;
          a2 += (f32x2){v2[jj], v2[jj]} * wj;
          a3 += (f32x2){v3[jj], v3[jj]} * wj;
        }
      }
      *(f32x2*)&LX[o][0][2 * cp] = a0;
      *(f32x2*)&LX[o][1][2 * cp] = a1;
      *(f32x2*)&LX[o][2][2 * cp] = a2;
      *(f32x2*)&LX[o][3][2 * cp] = a3;
      wavebar<true>(&cXZbar, epX);  // partials visible
      if (t >= RDEPTH) {
        while (__hip_atomic_load(&cCRITdone, __ATOMIC_RELAXED,
                                 __HIP_MEMORY_SCOPE_WORKGROUP) <
               4 * (t - RDEPTH + 1)) {
          __builtin_amdgcn_s_sleep(1);
        }
        asm volatile("" ::: "memory");
      }
      {
        const int b2 = idx >> 6, c3 = idx & 63;
        float ssum = 0.f;
#pragma unroll
        for (int oo = 0; oo < 8; ++oo) ssum += LX[oo][b2][c3];
        RING[t & (RDEPTH - 1)][b2][c3] = ssum;
      }
      wavebar<true>(&cXZbar, epX);  // reduce complete (guards LX overwrite)
      if (idx == 0) {
        asm volatile("s_waitcnt lgkmcnt(0)" ::: "memory");
        __hip_atomic_fetch_add(&cXZdone, 1, __ATOMIC_RELAXED,
                               __HIP_MEMORY_SCOPE_WORKGROUP);
      }
    }
  }
}

extern "C" void kernel_launch(void* const* d_in, const int* in_sizes, int n_in,
                              void* d_out, int out_size, void* d_ws, size_t ws_size,
                              hipStream_t stream) {
  const float* x    = (const float*)d_in[0];
  const float* Wk   = (const float*)d_in[1];
  const float* Wr   = (const float*)d_in[2];
  const float* bias = (const float*)d_in[3];
  float* out = (float*)d_out;

  // Sentinel-fill the h history (graph-capturable async memset).
  hipMemsetAsync(out, 0xFF, (size_t)out_size * sizeof(float), stream);
  lstm_persistent<<<256, 512, 0, stream>>>(x, Wk, Wr, bias, out);
}

// Round 13
// 4270.832 us; speedup vs baseline: 1.4301x; 1.1319x over previous
//
#include <hip/hip_runtime.h>

// LSTM forward, B=32 T=1024 D=512 U=512, fp32.
// Persistent fused kernel, 256 WGs x 512 thr (all co-resident, grid == #CUs).
// Group g = blockIdx&7 (batches 4g..4g+3); WG w = blockIdx>>3 owns units
// [16w,16w+16). Weights in VGPRs as f32x2 col-pairs.
//
// R13 = EXACT R9 (best, 4.27ms) with ONE variable changed: the 8-word
// sentinel data-poll is an asm block of global_load_dword sc0 sc1 (L1
// bypass + read the LLC coherence point) + a single s_waitcnt vmcnt(0),
// instead of 8 __hip_atomic_load(RELAXED, AGENT).
// Hypothesis under test: the atomic-load poll path can serve stale L1/L2
// lines (refreshing only on ambient eviction), inflating detect from
// ~1 RTT (0.75us, measured R7) to ~3.5us (R9's residual). sc0 sc1 forces
// every poll iteration to the coherence point -> detect ~1 RTT.

#define TT 1024
#define DD 512
#define UU 512
#define NCOL 2048
#define SENT 0xFFFFFFFFu
#define RDEPTH 4

typedef float f32x2 __attribute__((ext_vector_type(2)));
typedef float f32x4 __attribute__((ext_vector_type(4)));

__device__ __forceinline__ float hsig(float v) {
  return fminf(fmaxf(0.2f * v + 0.5f, 0.0f), 1.0f);
}
__device__ __forceinline__ float tanh_fast(float x) {
  float e = __expf(2.0f * x);
  return 1.0f - 2.0f / (e + 1.0f);
}

// Epoch barrier for the 4 waves of one half (waves 0-3 or 4-7).
template <bool SLEEP>
__device__ __forceinline__ void wavebar(int* ctr, int& ep) {
  asm volatile("s_waitcnt lgkmcnt(0)" ::: "memory");
  if ((threadIdx.x & 63) == 0)
    __hip_atomic_fetch_add(ctr, 1, __ATOMIC_RELAXED, __HIP_MEMORY_SCOPE_WORKGROUP);
  ep += 4;
  while (__hip_atomic_load(ctr, __ATOMIC_RELAXED, __HIP_MEMORY_SCOPE_WORKGROUP) < ep) {
    if (SLEEP) __builtin_amdgcn_s_sleep(1);
  }
  asm volatile("" ::: "memory");
}

__global__ __launch_bounds__(512, 2) void lstm_persistent(
    const float* __restrict__ x,
    const float* __restrict__ Wk,
    const float* __restrict__ Wr,
    const float* __restrict__ bias,
    float* __restrict__ out) {
  const int tid = (int)threadIdx.x;
  const int g   = (int)blockIdx.x & 7;
  const int w   = (int)blockIdx.x >> 3;
  const bool crit = (tid < 256);
  const int l   = tid & 63;

  __shared__ float LX[8][4][65];
  __shared__ float LR[2][8][4][66];
  __shared__ float RING[RDEPTH][4][66];
  __shared__ float LH[4][8][68];
  __shared__ float LB[64];
  __shared__ int cXZdone, cCRITdone, cXZbar, cCRITbar;

  if (tid == 0) { cXZdone = 0; cCRITdone = 0; cXZbar = 0; cCRITbar = 0; }
  if (tid < 64) LB[tid] = bias[(tid >> 4) * UU + w * 16 + (tid & 15)];

  f32x2 W2[64];
  {
    const int wv  = tid >> 6;
    const int idx = tid & 255;
    const int cp  = crit ? (l & 31) : (idx & 31);
    const int ko  = crit ? (2 * (wv & 3) + (l >> 5)) : (idx >> 5);
    const int gcb = (cp >> 3) * UU + w * 16 + ((2 * cp) & 15);
    const float* M = crit ? Wr : Wk;
#pragma unroll
    for (int j = 0; j < 64; ++j)
      W2[j] = *(const f32x2*)(M + (size_t)(64 * ko + j) * NCOL + gcb);
  }
  __syncthreads();  // one-time init barrier only

  if (crit) {
    // ---------------- critical path: waves 0-3 ----------------
    const int wv  = tid >> 6;        // wave id; poll-slice + batch wv
    const int kq0 = 2 * wv;
    const int kql = kq0 + (l >> 5);
    const int cp  = l & 31;
    const unsigned* ou0 = (const unsigned*)out + (size_t)(g * 4 + 0) * TT * UU;
    const unsigned* ou1 = (const unsigned*)out + (size_t)(g * 4 + 1) * TT * UU;
    const unsigned* ou2 = (const unsigned*)out + (size_t)(g * 4 + 2) * TT * UU;
    const unsigned* ou3 = (const unsigned*)out + (size_t)(g * 4 + 3) * TT * UU;
    float c_state = 0.0f;            // lanes 0-15: c for (batch wv, unit l)
    int epC = 0;

    for (int t = 0; t < TT; ++t) {
      if (t > 0) {
        // ---- slice-local data-poll: 8 words, 1 RTT, 8 producer WGs ----
        // asm sc0 sc1: bypass L1, read the LLC coherence point every iter.
        const size_t roff = (size_t)(t - 1) * UU + 128 * wv + l;
        const unsigned* p0 = ou0 + roff;
        const unsigned* p1 = ou1 + roff;
        const unsigned* p2 = ou2 + roff;
        const unsigned* p3 = ou3 + roff;
        unsigned v0, v1, v2, v3, v4, v5, v6, v7;
        for (;;) {
          asm volatile(
              "global_load_dword %0, %8, off sc0 sc1\n\t"
              "global_load_dword %1, %8, off offset:256 sc0 sc1\n\t"
              "global_load_dword %2, %9, off sc0 sc1\n\t"
              "global_load_dword %3, %9, off offset:256 sc0 sc1\n\t"
              "global_load_dword %4, %10, off sc0 sc1\n\t"
              "global_load_dword %5, %10, off offset:256 sc0 sc1\n\t"
              "global_load_dword %6, %11, off sc0 sc1\n\t"
              "global_load_dword %7, %11, off offset:256 sc0 sc1\n\t"
              "s_waitcnt vmcnt(0)"
              : "=v"(v0), "=v"(v1), "=v"(v2), "=v"(v3),
                "=v"(v4), "=v"(v5), "=v"(v6), "=v"(v7)
              : "v"(p0), "v"(p1), "v"(p2), "v"(p3)
              : "memory");
          int ok = (v0 != SENT) & (v1 != SENT) & (v2 != SENT) & (v3 != SENT) &
                   (v4 != SENT) & (v5 != SENT) & (v6 != SENT) & (v7 != SENT);
          if (__all(ok)) break;
          __builtin_amdgcn_s_sleep(1);
        }
        // ---- stage into this wave's private LH octants ----
        LH[0][kq0    ][l] = __uint_as_float(v0);
        LH[0][kq0 + 1][l] = __uint_as_float(v1);
        LH[1][kq0    ][l] = __uint_as_float(v2);
        LH[1][kq0 + 1][l] = __uint_as_float(v3);
        LH[2][kq0    ][l] = __uint_as_float(v4);
        LH[2][kq0 + 1][l] = __uint_as_float(v5);
        LH[3][kq0    ][l] = __uint_as_float(v6);
        LH[3][kq0 + 1][l] = __uint_as_float(v7);
        asm volatile("s_waitcnt lgkmcnt(0)" ::: "memory");
        __builtin_amdgcn_sched_barrier(0);
        // ---- dot: 2 cols x 64 k x 4 batches, f32x2 acc (v_pk_fma) ----
        __builtin_amdgcn_s_setprio(1);
        f32x2 a0 = {0.f, 0.f}, a1 = {0.f, 0.f}, a2 = {0.f, 0.f}, a3 = {0.f, 0.f};
#pragma unroll
        for (int j4 = 0; j4 < 16; ++j4) {
          f32x4 h0 = *(const f32x4*)&LH[0][kql][4 * j4];
          f32x4 h1 = *(const f32x4*)&LH[1][kql][4 * j4];
          f32x4 h2 = *(const f32x4*)&LH[2][kql][4 * j4];
          f32x4 h3 = *(const f32x4*)&LH[3][kql][4 * j4];
#pragma unroll
          for (int jj = 0; jj < 4; ++jj) {
            f32x2 wj = W2[4 * j4 + jj];
            a0 += (f32x2){h0[jj], h0[jj]} * wj;
            a1 += (f32x2){h1[jj], h1[jj]} * wj;
            a2 += (f32x2){h2[jj], h2[jj]} * wj;
            a3 += (f32x2){h3[jj], h3[jj]} * wj;
          }
        }
        __builtin_amdgcn_s_setprio(0);
        const int p = t & 1;
        *(f32x2*)&LR[p][kql][0][2 * cp] = a0;
        *(f32x2*)&LR[p][kql][1][2 * cp] = a1;
        *(f32x2*)&LR[p][kql][2][2 * cp] = a2;
        *(f32x2*)&LR[p][kql][3][2 * cp] = a3;
      }
      // ---- pre-gate: xz + bias for batch wv (lanes 0-15), before B2 ----
      float s0 = 0.f, s1 = 0.f, s2 = 0.f, s3 = 0.f;
      if (l < 16) {
        while (__hip_atomic_load(&cXZdone, __ATOMIC_RELAXED,
                                 __HIP_MEMORY_SCOPE_WORKGROUP) < t + 1) {
        }
        asm volatile("" ::: "memory");
        const int ss = t & (RDEPTH - 1);
        s0 = RING[ss][wv][l +  0] + LB[l +  0];
        s1 = RING[ss][wv][l + 16] + LB[l + 16];
        s2 = RING[ss][wv][l + 32] + LB[l + 32];
        s3 = RING[ss][wv][l + 48] + LB[l + 48];
      }
      wavebar<false>(&cCRITbar, epC);  // B2: all LR partials complete
      if (l == 0)
        __hip_atomic_fetch_add(&cCRITdone, 1, __ATOMIC_RELAXED,
                               __HIP_MEMORY_SCOPE_WORKGROUP);
      // ---- gates for batch wv, units w*16 + l (lanes 0-15) ----
      if (l < 16) {
        if (t > 0) {
          const int p = t & 1;
#pragma unroll
          for (int kq = 0; kq < 8; ++kq) {
            s0 += LR[p][kq][wv][l +  0];
            s1 += LR[p][kq][wv][l + 16];
            s2 += LR[p][kq][wv][l + 32];
            s3 += LR[p][kq][wv][l + 48];
          }
        }
        float gi = hsig(s0);
        float gf = hsig(s1);
        float gc = tanh_fast(s2);
        float go = hsig(s3);
        c_state = gf * c_state + gi * gc;
        float h = go * tanh_fast(c_state);
        __hip_atomic_store(
            out + ((size_t)(g * 4 + wv) * TT + t) * UU + w * 16 + l, h,
            __ATOMIC_RELAXED, __HIP_MEMORY_SCOPE_AGENT);
      }
    }
  } else {
    // ---------------- xz pipeline: waves 4-7 (free-running) ----------------
    const int idx = tid & 255;
    const int o   = idx >> 5;
    const int cp  = idx & 31;
    const float* xb0 = x + (size_t)(g * 4 + 0) * TT * DD + o * 64;
    const float* xb1 = x + (size_t)(g * 4 + 1) * TT * DD + o * 64;
    const float* xb2 = x + (size_t)(g * 4 + 2) * TT * DD + o * 64;
    const float* xb3 = x + (size_t)(g * 4 + 3) * TT * DD + o * 64;
    int epX = 0;

    for (int t = 0; t < TT; ++t) {
      const size_t off = (size_t)t * DD;
      f32x2 a0 = {0.f, 0.f}, a1 = {0.f, 0.f}, a2 = {0.f, 0.f}, a3 = {0.f, 0.f};
#pragma unroll
      for (int j4 = 0; j4 < 16; ++j4) {
        f32x4 v0 = *(const f32x4*)(xb0 + off + 4 * j4);
        f32x4 v1 = *(const f32x4*)(xb1 + off + 4 * j4);
        f32x4 v2 = *(const f32x4*)(xb2 + off + 4 * j4);
        f32x4 v3 = *(const f32x4*)(xb3 + off + 4 * j4);
#pragma unroll
        for (int jj = 0; jj < 4; ++jj) {
          f32x2 wj = W2[4 * j4 + jj];
          a0 += (f32x2){v0[jj], v0[jj]} * wj;
          a1 += (f32x2){v1[jj], v1[jj]} * wj;
          a2 += (f32x2){v2[jj], v2[jj]} * wj;
          a3 += (f32x2){v3[jj], v3[jj]} * wj;
        }
      }
      *(f32x2*)&LX[o][0][2 * cp] = a0;
      *(f32x2*)&LX[o][1][2 * cp] = a1;
      *(f32x2*)&LX[o][2][2 * cp] = a2;
      *(f32x2*)&LX[o][3][2 * cp] = a3;
      wavebar<true>(&cXZbar, epX);  // partials visible
      if (t >= RDEPTH) {
        while (__hip_atomic_load(&cCRITdone, __ATOMIC_RELAXED,
                                 __HIP_MEMORY_SCOPE_WORKGROUP) <
               4 * (t - RDEPTH + 1)) {
          __builtin_amdgcn_s_sleep(1);
        }
        asm volatile("" ::: "memory");
      }
      {
        const int b2 = idx >> 6, c3 = idx & 63;
        float ssum = 0.f;
#pragma unroll
        for (int oo = 0; oo < 8; ++oo) ssum += LX[oo][b2][c3];
        RING[t & (RDEPTH - 1)][b2][c3] = ssum;
      }
      wavebar<true>(&cXZbar, epX);  // reduce complete (guards LX overwrite)
      if (idx == 0) {
        asm volatile("s_waitcnt lgkmcnt(0)" ::: "memory");
        __hip_atomic_fetch_add(&cXZdone, 1, __ATOMIC_RELAXED,
                               __HIP_MEMORY_SCOPE_WORKGROUP);
      }
    }
  }
}

extern "C" void kernel_launch(void* const* d_in, const int* in_sizes, int n_in,
                              void* d_out, int out_size, void* d_ws, size_t ws_size,
                              hipStream_t stream) {
  const float* x    = (const float*)d_in[0];
  const float* Wk   = (const float*)d_in[1];
  const float* Wr   = (const float*)d_in[2];
  const float* bias = (const float*)d_in[3];
  float* out = (float*)d_out;

  // Sentinel-fill the h history (graph-capturable async memset).
  hipMemsetAsync(out, 0xFF, (size_t)out_size * sizeof(float), stream);
  lstm_persistent<<<256, 512, 0, stream>>>(x, Wk, Wr, bias, out);
}